// Round 10
// baseline (736.450 us; speedup 1.0000x reference)
//
#include <hip/hip_runtime.h>

// ProjConvReducedI2T — R9 (resubmit after infra timeout): grid-widening round.
// fc: 8 l-slices × 4-cap groups (grid 4-8x); conv/mix: 2-cap loop, bc=64.

#define EPSc 1e-5f
typedef unsigned short u16;
typedef __bf16 bf16x8 __attribute__((ext_vector_type(8)));
typedef float f32x4 __attribute__((ext_vector_type(4)));

// fixed ws offsets (floats)
static const long OFF_IMG_GLOBAL = 0;        // 32768
static const long OFF_IV         = 32768;    // 32768
static const long OFF_IMG_VEC    = 65536;    // 4096
static const long OFF_CAP_RED    = 69632;    // 1048576  fp32 [128b][128c][64t]
static const long OFF_KERN       = 1118208;  // 1048576  scratch: part/scsh0/scsh1/pp
static const long OFF_KERN_BF    = 2166784;  // 524288 fl = bf16 [j][i][g][kp][64o][64c']
static const long OFF_CA_BF      = 2691072;  // 16384 fl
static const long OFF_C1W0      = 2707456;   // 8192 fl  (c1_W[0][:, :128])
static const long OFF_C1W0X     = 2715648;   // 8192 fl  (c1_W[0][:, 128:])
static const long OFF_C1W1      = 2723840;   // 16384 fl (c1_W[1] full)
static const long OFF_WFC       = 2740224;   // 65536 fl
static const long OFF_CAP_BF    = 2805760;   // 532544 fl : bf16 [128b][65t][128c]
static const long OFF_SHARED1   = 3338304;   // 1048576 fp32 [128b][64t][128o]
static const long OFF_SCSHS     = 4386880;   // 256 (shared-branch sc/sh)
static const long FIXED_END     = 4387136;

__device__ inline u16 f2bf(float f) {
  union { float f; unsigned u; } v; v.f = f;
  unsigned u = v.u;
  return (u16)((u + 0x7FFFu + ((u >> 16) & 1u)) >> 16);
}
__device__ inline float bf2f(u16 u) {
  union { unsigned u; float f; } v; v.u = ((unsigned)u) << 16; return v.f;
}

// ---- img_global + iv ----
__global__ void k_img(const float* __restrict__ img, float* __restrict__ img_global,
                      float* __restrict__ iv) {
  int b = blockIdx.x, tid = threadIdx.x;
  __shared__ float gl[1024];
  __shared__ float red[256];
  float ssq = 0.f;
  for (int l = tid; l < 1024; l += 256) {
    float s = 0.f;
    for (int p = 0; p < 36; ++p) s += img[((long)b*36 + p)*1024 + l];
    float g = s * (1.f/36.f);
    gl[l] = g;
    img_global[(long)b*1024 + l] = g;
    ssq += g*g;
  }
  red[tid] = ssq;
  __syncthreads();
  for (int off = 128; off > 0; off >>= 1) {
    if (tid < off) red[tid] += red[tid+off];
    __syncthreads();
  }
  float inv = rsqrtf(red[0]);
  for (int l = tid; l < 1024; l += 256) iv[(long)b*1024 + l] = gl[l]*inv;
}

// ---- img_vec ----
__global__ void k_imgvec(const float* __restrict__ img_global, const float* __restrict__ W_ri,
                         const float* __restrict__ b_ri, float* __restrict__ img_vec) {
  int b = blockIdx.x, tid = threadIdx.x;
  __shared__ float gl[1024];
  for (int l = tid; l < 1024; l += 128) gl[l] = img_global[(long)b*1024 + l];
  __syncthreads();
  const float* w = W_ri + (long)tid*1024;
  float acc = b_ri[tid];
  for (int l = 0; l < 1024; l += 4) {
    float4 wv = *(const float4*)(w + l);
    float4 gv = *(const float4*)(gl + l);
    acc += wv.x*gv.x + wv.y*gv.y + wv.z*gv.z + wv.w*gv.w;
  }
  img_vec[(long)b*128 + tid] = acc;
}

// ---- cap_red fp32 [b][c][t] ----
__global__ void k_capred(const float* __restrict__ cap, const float* __restrict__ W_rt,
                         const float* __restrict__ b_rt, float* __restrict__ cap_red) {
  int tg = blockIdx.x, b = blockIdx.y, tid = threadIdx.x;
  __shared__ float xs[300*16];
  for (int idx = tid; idx < 16*300; idx += 128) {
    int q = idx / 300, c = idx - q*300;
    xs[c*16 + q] = cap[((long)b*64 + tg*16 + q)*300 + c];
  }
  __syncthreads();
  int o = tid;
  const float* w = W_rt + (long)o*300;
  float acc[16];
  float bb = b_rt[o];
  #pragma unroll
  for (int q = 0; q < 16; ++q) acc[q] = bb;
  for (int c = 0; c < 300; ++c) {
    float wv = w[c];
    const float* xp = &xs[c*16];
    float4 x0 = *(const float4*)(xp);
    float4 x1 = *(const float4*)(xp+4);
    float4 x2 = *(const float4*)(xp+8);
    float4 x3 = *(const float4*)(xp+12);
    acc[0]+=wv*x0.x; acc[1]+=wv*x0.y; acc[2]+=wv*x0.z; acc[3]+=wv*x0.w;
    acc[4]+=wv*x1.x; acc[5]+=wv*x1.y; acc[6]+=wv*x1.z; acc[7]+=wv*x1.w;
    acc[8]+=wv*x2.x; acc[9]+=wv*x2.y; acc[10]+=wv*x2.z; acc[11]+=wv*x2.w;
    acc[12]+=wv*x3.x; acc[13]+=wv*x3.y; acc[14]+=wv*x3.z; acc[15]+=wv*x3.w;
  }
  float* outp = cap_red + ((long)b*128 + o)*64 + tg*16;
  #pragma unroll
  for (int q = 0; q < 16; ++q) outp[q] = acc[q];
}

// ---- cap_red -> cap_bf bf16 [b][t(65)][c], row 64 zero ----
__global__ void k_cap2bf(const float* __restrict__ cap_red, u16* __restrict__ cap_bf) {
  int b = blockIdx.x, tid = threadIdx.x;
  __shared__ float ls[128*64];
  for (int idx = tid; idx < 8192; idx += 256) ls[idx] = cap_red[(long)b*8192 + idx];
  __syncthreads();
  for (int idx = tid; idx < 65*128; idx += 256) {
    int t = idx >> 7, c = idx & 127;
    float v = (t < 64) ? ls[c*64 + t] : 0.f;
    cap_bf[((long)b*65 + t)*128 + c] = f2bf(v);
  }
}

// ---- fused hypernet kernel gen + BN + bf16 deinterleave ----
__global__ void k_kerngen2(const float* __restrict__ mk_W, const float* __restrict__ mk_b,
                           const float* __restrict__ wn_g, const float* __restrict__ wn_b,
                           const float* __restrict__ img_vec, u16* __restrict__ kbf) {
  int j = blockIdx.x >> 7, o = blockIdx.x & 127, c = threadIdx.x;
  __shared__ float bl[128*32];    // [r][i]
  __shared__ float ls[128*33];    // [c][i] padded
  __shared__ float ssc[32], ssh[32];
  for (int idx = c; idx < 4096; idx += 128) {
    int i = idx >> 7, r = idx & 127;
    bl[r*32 + i] = img_vec[idx];
  }
  __syncthreads();
  const float* wrow = mk_W + ((long)(j*16384 + o*128 + c))*128;
  float acc[32];
  #pragma unroll
  for (int i = 0; i < 32; ++i) acc[i] = 0.f;
  for (int r = 0; r < 128; ++r) {
    float w = wrow[r];
    const float* bp = &bl[r*32];
    #pragma unroll
    for (int i = 0; i < 32; ++i) acc[i] += w * bp[i];
  }
  float kb_ = mk_b[j*16384 + o*128 + c];
  #pragma unroll
  for (int i = 0; i < 32; ++i) ls[c*33 + i] = acc[i] + kb_;
  __syncthreads();
  if (c < 32) {
    int i = c;
    float s = 0.f, q = 0.f;
    for (int cc = 0; cc < 128; ++cc) { float v = ls[cc*33 + i]; s += v; q += v*v; }
    float mean = s * (1.f/128.f);
    float var = q * (1.f/128.f) - mean*mean;
    float sc = wn_g[j*128+o] * rsqrtf(var + EPSc);
    ssc[i] = sc;
    ssh[i] = wn_b[j*128+o] - mean*sc;
  }
  __syncthreads();
  int g = o >> 6, op = o & 63, kp = c & 1, cp = c >> 1;
  for (int i = 0; i < 32; ++i) {
    float v = ls[c*33 + i]*ssc[i] + ssh[i];
    kbf[((long)((j*32+i)*2 + g)*2 + kp)*4096 + op*64 + cp] = f2bf(v);
  }
}

// ---- ca_W -> bf16 deinterleaved [j][g][kp][64o][64c'] ----
__global__ void k_ca2bf(const float* __restrict__ caW, u16* __restrict__ cabf) {
  int idx = blockIdx.x*256 + threadIdx.x; // < 32768
  int j = idx >> 14, r = idx & 16383;
  int o = r >> 7, ck = r & 127, cp = ck >> 1, kp = ck & 1;
  int g = o >> 6, op = o & 63;
  cabf[(((long)(j*2+g)*2 + kp))*4096 + op*64 + cp] = f2bf(caW[idx]);
}

// ---- c1_W -> bf16: w0a=[0][:, :128], w0x=[0][:,128:], w1=[1] full ----
__global__ void k_c1bf(const float* __restrict__ c1W, u16* __restrict__ w0a,
                       u16* __restrict__ w0x, u16* __restrict__ w1) {
  int idx = blockIdx.x*256 + threadIdx.x; // < 65536
  u16 v = f2bf(c1W[idx]);
  if (idx < 32768) {
    int o = idx >> 8, c = idx & 255;
    if (c < 128) w0a[o*128 + c] = v; else w0x[o*128 + (c-128)] = v;
  } else {
    w1[idx - 32768] = v;
  }
}

// ---- W_fc -> bf16 ----
__global__ void k_wfc2bf(const float* __restrict__ W, u16* __restrict__ out) {
  int idx = (blockIdx.x*256 + threadIdx.x)*4;
  float4 v = *(const float4*)(W + idx);
  u16 o[4] = { f2bf(v.x), f2bf(v.y), f2bf(v.z), f2bf(v.w) };
  *(uint2*)(out + idx) = *(const uint2*)(o);
}

// ---- MFMA grouped conv, caption-loop (2/block), partial stats ----
// grid (64, V, NI). part layout: [i][c][128] = 64 sums + 64 sumsqs.
__global__ __launch_bounds__(256) void k_conv_mfma2(
    const u16* __restrict__ X, long x_img_str, int tr_stride,
    const u16* __restrict__ kernA, const u16* __restrict__ statA,
    int tvalid, u16* __restrict__ H, int ctot, float* __restrict__ part) {
  int bc = blockIdx.x, v = blockIdx.y, i = blockIdx.z;
  int tid = threadIdx.x, w = tid >> 6, lane = tid & 63;
  int l15 = lane & 15, l4 = lane >> 4;
  int g = v & 1;
  const u16* A = (v >= 2) ? (statA + (long)g*8192)
                          : (kernA + (long)i*16384 + (long)g*8192);
  __shared__ u16 xls[65*64];
  bf16x8 af[2][2];
  #pragma unroll
  for (int kp = 0; kp < 2; ++kp)
    #pragma unroll
    for (int ks = 0; ks < 2; ++ks)
      af[kp][ks] = *(const bf16x8*)(A + ((long)(kp*64 + w*16 + l15))*64 + ks*32 + l4*8);
  int cbase = v*64 + w*16;
  float s[4] = {0.f,0.f,0.f,0.f}, q[4] = {0.f,0.f,0.f,0.f};
  for (int bb = 0; bb < 2; ++bb) {
    int b = bc*2 + bb;
    const u16* src = X + x_img_str*i + ((long)b*tr_stride)*128 + g*64;
    __syncthreads();
    for (int idx = tid; idx < 65*8; idx += 256) {
      int r = idx >> 3, ch = idx & 7;
      uint4 d = *(const uint4*)(src + (long)r*128 + ch*8);
      *(uint4*)(xls + r*64 + ((ch ^ (r & 7))*8)) = d;
    }
    __syncthreads();
    #pragma unroll
    for (int nt = 0; nt < 4; ++nt) {
      f32x4 acc = {0.f,0.f,0.f,0.f};
      #pragma unroll
      for (int kp = 0; kp < 2; ++kp) {
        int row = nt*16 + l15 + kp;
        #pragma unroll
        for (int ks = 0; ks < 2; ++ks) {
          int ch = (ks*4 + l4) ^ (row & 7);
          bf16x8 bf = *(const bf16x8*)(xls + row*64 + ch*8);
          acc = __builtin_amdgcn_mfma_f32_16x16x32_bf16(af[kp][ks], bf, acc, 0, 0, 0);
        }
      }
      int t = nt*16 + l15;
      u16 h4[4] = { f2bf(acc[0]), f2bf(acc[1]), f2bf(acc[2]), f2bf(acc[3]) };
      *(uint2*)(H + ((long)((i*128 + b)*64 + t))*ctot + cbase + l4*4) = *(const uint2*)(h4);
      float m = (t < tvalid) ? 1.f : 0.f;
      #pragma unroll
      for (int r = 0; r < 4; ++r) {
        float vv = acc[r]*m;
        s[r] += vv; q[r] += vv*vv;
      }
    }
  }
  #pragma unroll
  for (int r = 0; r < 4; ++r) {
    #pragma unroll
    for (int mk = 1; mk < 16; mk <<= 1) {
      s[r] += __shfl_xor(s[r], mk);
      q[r] += __shfl_xor(q[r], mk);
    }
  }
  if (l15 == 0) {
    #pragma unroll
    for (int r = 0; r < 4; ++r) {
      int c = cbase + l4*4 + r;
      long base = ((long)i*ctot + c)*128;
      part[base + bc] = s[r];
      part[base + 64 + bc] = q[r];
    }
  }
}

// ---- reduce 64 partials -> (sc,sh) ----
__global__ void k_finstats2(const float* __restrict__ part, float* __restrict__ scsh,
                            const float* __restrict__ g, const float* __restrict__ bta,
                            int ct, float n, int total) {
  int idx = blockIdx.x*256 + threadIdx.x;
  if (idx >= total) return;
  int c = idx & (ct - 1);
  const float* p = part + (long)idx*128;
  float s = 0.f, q = 0.f;
  #pragma unroll
  for (int k = 0; k < 64; ++k) { s += p[k]; q += p[64+k]; }
  float mean = s / n, var = q / n - mean*mean;
  float sc = g[c] * rsqrtf(var + EPSc);
  scsh[idx*2] = sc;
  scsh[idx*2 + 1] = bta[c] - mean*sc;
}

// ---- MFMA 1x1 mix + fused bn/relu, caption-loop (2/block) ----
// F32OUT=true: write fp32 (shared1 path). Else bf16 + c1b + optional addbuf.
template<int CK, bool F32OUT>
__global__ __launch_bounds__(256) void k_mix_mfma2(
    const u16* __restrict__ X, const u16* __restrict__ A,
    const float* __restrict__ scsh,
    const float* __restrict__ c1b, const float* __restrict__ addbuf,
    void* __restrict__ Qout, int tvalid) {
  constexpr int NCH = CK/8;
  constexpr int KST = CK/32;
  int bc = blockIdx.x, m = blockIdx.y, i = blockIdx.z;
  int tid = threadIdx.x, w = tid >> 6, lane = tid & 63;
  int l15 = lane & 15, l4 = lane >> 4;
  __shared__ u16 xls[64*CK];
  __shared__ float lsc[CK], lsh[CK];
  for (int c = tid; c < CK; c += 256) {
    lsc[c] = scsh[((long)i*CK + c)*2];
    lsh[c] = scsh[((long)i*CK + c)*2 + 1];
  }
  int oa = m*64 + w*16 + l15;
  bf16x8 af[KST];
  #pragma unroll
  for (int ks = 0; ks < KST; ++ks)
    af[ks] = *(const bf16x8*)(A + (long)oa*CK + ks*32 + l4*8);
  int ob = m*64 + w*16 + l4*4;
  float4 cb = {0.f,0.f,0.f,0.f};
  if (c1b) { cb.x = c1b[ob]; cb.y = c1b[ob+1]; cb.z = c1b[ob+2]; cb.w = c1b[ob+3]; }
  for (int bb = 0; bb < 2; ++bb) {
    int b = bc*2 + bb;
    const u16* src = X + ((long)(i*128 + b)*64)*CK;
    __syncthreads();
    for (int idx = tid; idx < 64*NCH; idx += 256) {
      int r = idx / NCH, ch = idx & (NCH - 1);
      uint4 d = *(const uint4*)(src + (long)r*CK + ch*8);
      unsigned dd[4] = {d.x, d.y, d.z, d.w};
      int c0 = ch*8;
      u16 o[8];
      #pragma unroll
      for (int pi = 0; pi < 4; ++pi) {
        float v0 = bf2f((u16)(dd[pi] & 0xFFFF));
        float v1 = bf2f((u16)(dd[pi] >> 16));
        v0 = fmaxf(v0*lsc[c0 + pi*2] + lsh[c0 + pi*2], 0.f);
        v1 = fmaxf(v1*lsc[c0 + pi*2 + 1] + lsh[c0 + pi*2 + 1], 0.f);
        o[pi*2] = f2bf(v0); o[pi*2 + 1] = f2bf(v1);
      }
      *(uint4*)(xls + r*CK + (((ch ^ (r & 15)) & (NCH - 1))*8)) = *(const uint4*)o;
    }
    __syncthreads();
    #pragma unroll
    for (int nt = 0; nt < 4; ++nt) {
      f32x4 acc = {0.f,0.f,0.f,0.f};
      int row = nt*16 + l15;
      #pragma unroll
      for (int ks = 0; ks < KST; ++ks) {
        int ch = ((ks*4 + l4) ^ (row & 15)) & (NCH - 1);
        bf16x8 bf = *(const bf16x8*)(xls + row*CK + ch*8);
        acc = __builtin_amdgcn_mfma_f32_16x16x32_bf16(af[ks], bf, acc, 0, 0, 0);
      }
      int t = row;
      if (t < tvalid) {
        if constexpr (F32OUT) {
          float4 o4 = { acc[0]+cb.x, acc[1]+cb.y, acc[2]+cb.z, acc[3]+cb.w };
          *(float4*)((float*)Qout + ((long)((i*128 + b)*64 + t))*128 + ob) = o4;
        } else {
          float4 ad = {0.f,0.f,0.f,0.f};
          if (addbuf) ad = *(const float4*)(addbuf + ((long)b*64 + t)*128 + ob);
          u16 h4[4] = { f2bf(acc[0] + cb.x + ad.x), f2bf(acc[1] + cb.y + ad.y),
                        f2bf(acc[2] + cb.z + ad.z), f2bf(acc[3] + cb.w + ad.w) };
          *(uint2*)((u16*)Qout + ((long)((i*128 + b)*64 + t))*128 + ob) = *(const uint2*)(h4);
        }
      }
    }
  }
}

// ---- fc: W_fc-resident waves (32 l's each), barrier-free, per-wave partials ----
// grid (32 capgrp of 4, 8 lslice, NI). pp: [i][b][32][2].
__global__ __launch_bounds__(256) void k_fc6(
    const u16* __restrict__ Qt, const u16* __restrict__ Wb,
    const float* __restrict__ bfc, const float* __restrict__ ivp,
    float* __restrict__ pp) {
  int bg = blockIdx.x, sl = blockIdx.y, i = blockIdx.z;
  int tid = threadIdx.x, w = tid >> 6, lane = tid & 63;
  int l15 = lane & 15, l4 = lane >> 4;
  int lbase = sl*128 + w*32;
  bf16x8 wf[2][4];
  #pragma unroll
  for (int lt = 0; lt < 2; ++lt)
    #pragma unroll
    for (int ks = 0; ks < 4; ++ks)
      wf[lt][ks] = *(const bf16x8*)(Wb + (long)(lbase + lt*16 + l15)*128 + ks*32 + l4*8);
  float bfr[2], ivr[2];
  const float* ivb = ivp + (long)i*1024;
  #pragma unroll
  for (int lt = 0; lt < 2; ++lt) {
    bfr[lt] = bfc[lbase + lt*16 + l15];
    ivr[lt] = ivb[lbase + lt*16 + l15];
  }
  for (int bb = 0; bb < 4; ++bb) {
    int b = bg*4 + bb;
    const u16* Qb = Qt + ((long)(i*128 + b))*8192;
    float mx[2] = {-3e38f, -3e38f};
    #pragma unroll
    for (int nt = 0; nt < 4; ++nt) {
      bf16x8 qf[4];
      #pragma unroll
      for (int ks = 0; ks < 4; ++ks)
        qf[ks] = *(const bf16x8*)(Qb + (nt*16 + l15)*128 + ks*32 + l4*8);
      #pragma unroll
      for (int lt = 0; lt < 2; ++lt) {
        f32x4 acc = {0.f,0.f,0.f,0.f};
        acc = __builtin_amdgcn_mfma_f32_16x16x32_bf16(qf[0], wf[lt][0], acc, 0,0,0);
        acc = __builtin_amdgcn_mfma_f32_16x16x32_bf16(qf[1], wf[lt][1], acc, 0,0,0);
        acc = __builtin_amdgcn_mfma_f32_16x16x32_bf16(qf[2], wf[lt][2], acc, 0,0,0);
        acc = __builtin_amdgcn_mfma_f32_16x16x32_bf16(qf[3], wf[lt][3], acc, 0,0,0);
        // D[row t = nt*16 + l4*4 + r][col l = lbase + lt*16 + l15]
        float m01 = fmaxf(acc[0], acc[1]);
        float m23 = fmaxf(acc[2], acc[3]);
        if (nt == 3 && l4 == 3) m23 = -3e38f;   // t=62,63 invalid
        mx[lt] = fmaxf(mx[lt], fmaxf(m01, m23));
      }
    }
    float ssc = 0.f, ddc = 0.f;
    #pragma unroll
    for (int lt = 0; lt < 2; ++lt) {
      float m = mx[lt];
      m = fmaxf(m, __shfl_xor(m, 16));
      m = fmaxf(m, __shfl_xor(m, 32));
      float tv = m + bfr[lt];   // exact on lanes 0-15
      ssc += tv*tv;
      ddc += tv*ivr[lt];
    }
    #pragma unroll
    for (int mk = 1; mk < 16; mk <<= 1) { ssc += __shfl_xor(ssc, mk); ddc += __shfl_xor(ddc, mk); }
    if (lane == 0) {
      long o = (((long)i*128 + b)*32 + sl*4 + w)*2;
      pp[o] = ssc; pp[o+1] = ddc;
    }
  }
}

// ---- final: sum 32 partials -> sims ----
__global__ void k_fcred(const float* __restrict__ pp, float* __restrict__ outp) {
  int i = blockIdx.x, b = threadIdx.x;
  const float* p = pp + ((long)i*128 + b)*64;
  float S = 0.f, D = 0.f;
  #pragma unroll
  for (int k = 0; k < 32; ++k) { S += p[k*2]; D += p[k*2+1]; }
  outp[i*128 + b] = D * rsqrtf(S);
}

extern "C" void kernel_launch(void* const* d_in, const int* in_sizes, int n_in,
                              void* d_out, int out_size, void* d_ws, size_t ws_size,
                              hipStream_t stream) {
  (void)in_sizes; (void)n_in; (void)out_size;
  const float* img_embed = (const float*)d_in[0];
  const float* cap_embed = (const float*)d_in[1];
  const float* W_ri  = (const float*)d_in[2];
  const float* b_ri  = (const float*)d_in[3];
  const float* W_rt  = (const float*)d_in[4];
  const float* b_rt  = (const float*)d_in[5];
  const float* mk_W  = (const float*)d_in[6];
  const float* mk_b  = (const float*)d_in[7];
  const float* wn_g  = (const float*)d_in[10];
  const float* wn_b  = (const float*)d_in[11];
  const float* ca_W  = (const float*)d_in[12];
  const float* bn_g  = (const float*)d_in[14];
  const float* bn_b  = (const float*)d_in[15];
  const float* c1_W  = (const float*)d_in[16];
  const float* c1_b  = (const float*)d_in[17];
  const float* W_fc  = (const float*)d_in[18];
  const float* b_fc  = (const float*)d_in[19];
  float* out = (float*)d_out;
  float* ws  = (float*)d_ws;

  float* img_global = ws + OFF_IMG_GLOBAL;
  float* iv       = ws + OFF_IV;
  float* img_vec  = ws + OFF_IMG_VEC;
  float* cap_red  = ws + OFF_CAP_RED;
  u16*   kern_bf  = (u16*)(ws + OFF_KERN_BF);
  u16*   ca_bf    = (u16*)(ws + OFF_CA_BF);
  u16*   c1w0a    = (u16*)(ws + OFF_C1W0);
  u16*   c1w0x    = (u16*)(ws + OFF_C1W0X);
  u16*   c1w1     = (u16*)(ws + OFF_C1W1);
  u16*   wfcb     = (u16*)(ws + OFF_WFC);
  u16*   cap_bf   = (u16*)(ws + OFF_CAP_BF);
  float* shared1  = ws + OFF_SHARED1;
  float* scshS    = ws + OFF_SCSHS;

  // choose images-per-pass from ws_size (deterministic -> graph-safe); max 16
  int NC = 4;
  {
    auto need = [](long nc) -> size_t { return (size_t)(FIXED_END + nc*2621440L + 128) * 4u; };
    if (ws_size >= need(16)) NC = 16;
    else if (ws_size >= need(8)) NC = 8;
  }

  // scratch region: stats partials (64 slots) + scsh + fc partials
  float* part  = ws + OFF_KERN;                       // NC*256*128 <= 524288 fl
  float* scsh0 = ws + OFF_KERN + 524288;              // NC*256
  float* scsh1 = ws + OFF_KERN + 524288 + 8192;       // NC*512
  float* pp    = ws + OFF_KERN + 524288 + 8192 + 16384; // NC*8192

  // dynamic activation buffers
  long base = FIXED_END;
  u16* P0 = (u16*)(ws + base);
  u16* Q0 = (u16*)(ws + base + (long)NC*524288);
  u16* H1 = (u16*)(ws + base + (long)NC*524288*2 + 64);
  u16* Q1 = (u16*)(ws + base + (long)NC*524288*2 + 64 + (long)NC*1048576);
  u16* ax0bf = P0;   // prologue scratch (P0 region, free until main loop)

  // prologue
  k_img<<<32, 256, 0, stream>>>(img_embed, img_global, iv);
  k_imgvec<<<32, 128, 0, stream>>>(img_global, W_ri, b_ri, img_vec);
  k_capred<<<dim3(4,128), 128, 0, stream>>>(cap_embed, W_rt, b_rt, cap_red);
  k_cap2bf<<<128, 256, 0, stream>>>(cap_red, cap_bf);
  k_kerngen2<<<256, 128, 0, stream>>>(mk_W, mk_b, wn_g, wn_b, img_vec, kern_bf);
  k_ca2bf<<<128, 256, 0, stream>>>(ca_W, ca_bf);
  k_c1bf<<<256, 256, 0, stream>>>(c1_W, c1w0a, c1w0x, c1w1);
  k_wfc2bf<<<128, 256, 0, stream>>>(W_fc, wfcb);

  // shared layer-0 static branch (biases cancel in BN)
  k_conv_mfma2<<<dim3(64,2,1), 256, 0, stream>>>(
      cap_bf, 0L, 65, ca_bf, ca_bf, 63, ax0bf, 128, part);
  k_finstats2<<<1, 256, 0, stream>>>(part, scshS, bn_g + 128, bn_b + 128, 128, 8064.f, 128);
  k_mix_mfma2<128, true><<<dim3(64,2,1), 256, 0, stream>>>(
      ax0bf, c1w0x, scshS, nullptr, nullptr, shared1, 63);

  for (int ch = 0; ch < 32/NC; ++ch) {
    int i0 = ch*NC;
    // layer 0 dynamic conv
    k_conv_mfma2<<<dim3(64,2,NC), 256, 0, stream>>>(
        cap_bf, 0L, 65, kern_bf + (long)i0*16384, ca_bf, 63, P0, 128, part);
    k_finstats2<<<dim3((NC*128+255)/256), 256, 0, stream>>>(
        part, scsh0, bn_g, bn_b, 128, 8064.f, NC*128);
    k_mix_mfma2<128, false><<<dim3(64,2,NC), 256, 0, stream>>>(
        P0, c1w0a, scsh0, c1_b, shared1, Q0, 63);
    // layer 1: generated (v=0,1) + static (v=2,3)
    k_conv_mfma2<<<dim3(64,4,NC), 256, 0, stream>>>(
        Q0, 1048576L, 64, kern_bf + (long)(32 + i0)*16384, ca_bf + 16384, 62, H1, 256, part);
    k_finstats2<<<dim3((NC*256+255)/256), 256, 0, stream>>>(
        part, scsh1, bn_g + 256, bn_b + 256, 256, 7936.f, NC*256);
    k_mix_mfma2<256, false><<<dim3(64,2,NC), 256, 0, stream>>>(
        H1, c1w1, scsh1, c1_b + 128, nullptr, Q1, 62);
    // fc: weight-resident, barrier-free, wide grid
    k_fc6<<<dim3(32,8,NC), 256, 0, stream>>>(
        Q1, wfcb, b_fc, iv + (long)i0*1024, pp);
    k_fcred<<<NC, 128, 0, stream>>>(pp, out + i0*128);
  }
}